// Round 2
// baseline (13974.567 us; speedup 1.0000x reference)
//
#include <hip/hip_runtime.h>

// ---------------------------------------------------------------------------
// SDKT model: embeddings -> biLSTM encoder -> enc LSTM -> dec LSTM -> MLP head
// B=256, T=256, H=512, G=2048, enc/dec input = 288, enc2 input = 1024.
// All GEMMs bf16 MFMA (f32 accum); cell state f32; h stored bf16.
// Activations are TIME-MAJOR: [T][B][*]. xg computed in CH-step chunks to fit
// workspace (~296 MB at CH=32); decout is a CH-slot ring; head runs per-chunk.
// ---------------------------------------------------------------------------

using u16 = unsigned short;
using u32 = unsigned int;
typedef float f32x4 __attribute__((ext_vector_type(4)));
typedef __bf16 bf16x8 __attribute__((ext_vector_type(8)));

__device__ __forceinline__ u16 f2bf(float f) {
  u32 u = __float_as_uint(f);
  u = (u + 0x7FFFu + ((u >> 16) & 1u)) >> 16;  // RNE
  return (u16)u;
}
__device__ __forceinline__ float bf2f(u16 h) { return __uint_as_float(((u32)h) << 16); }
__device__ __forceinline__ float sigm(float x) { return 1.f / (1.f + __expf(-x)); }
__device__ __forceinline__ float tnh(float x) {
  float a = fabsf(x), e = __expf(-2.f * a);
  float t = (1.f - e) / (1.f + e);
  return x < 0.f ? -t : t;
}

// ---------------------------------------------------------------------------
// bf16 MFMA GEMM: C[M,N] = act(A[M,K] @ W[N,K]^T + bias[N]); A split at ksplit
// across two sources (pred_in = [dec_x[:,:160] | dec_out]). 64x64 tile, 4 waves.
// ---------------------------------------------------------------------------
template <int ACT>
__global__ __launch_bounds__(256) void gemm_k(
    const u16* __restrict__ A1, long lda1, const u16* __restrict__ A2, long lda2, int ksplit,
    const u16* __restrict__ W, long ldw, const float* __restrict__ bias,
    u16* __restrict__ C, long ldc, int K) {
  const int lane = threadIdx.x & 63;
  const int wv = threadIdx.x >> 6;
  const int lr = lane & 15, lg = lane >> 4;
  const long mbase = (long)blockIdx.y * 64 + (wv >> 1) * 32;
  const long nbase = (long)blockIdx.x * 64 + (wv & 1) * 32;
  f32x4 acc[2][2] = {};
  for (int kk = 0; kk < K; kk += 32) {
    const int k0 = kk + lg * 8;
    bf16x8 a[2], b[2];
#pragma unroll
    for (int fm = 0; fm < 2; fm++) {
      const long row = mbase + fm * 16 + lr;
      const u16* p = (k0 < ksplit) ? (A1 + row * lda1 + k0)
                                   : (A2 + row * lda2 + (k0 - ksplit));
      a[fm] = *reinterpret_cast<const bf16x8*>(p);
    }
#pragma unroll
    for (int fn = 0; fn < 2; fn++) {
      const long col = nbase + fn * 16 + lr;
      b[fn] = *reinterpret_cast<const bf16x8*>(W + col * ldw + k0);
    }
#pragma unroll
    for (int fm = 0; fm < 2; fm++)
#pragma unroll
      for (int fn = 0; fn < 2; fn++)
        acc[fm][fn] = __builtin_amdgcn_mfma_f32_16x16x32_bf16(a[fm], b[fn], acc[fm][fn], 0, 0, 0);
  }
#pragma unroll
  for (int fm = 0; fm < 2; fm++)
#pragma unroll
    for (int fn = 0; fn < 2; fn++)
#pragma unroll
      for (int r = 0; r < 4; r++) {
        const long row = mbase + fm * 16 + lg * 4 + r;  // C/D: row=(lane>>4)*4+reg
        const long col = nbase + fn * 16 + lr;          //      col=lane&15
        float v = acc[fm][fn][r] + bias[col];
        if (ACT == 1) v = tnh(v);
        C[row * ldc + col] = f2bf(v);
      }
}

// ---------------------------------------------------------------------------
// One LSTM time step: g = xg + h_prev @ w_hh^T; fused cell update.
// Block = 64 batch rows x 16 h-cols; grid = (32, 4, ndirs). MFMA output lane
// holds i,f,g,o for the SAME (row,col) -> no cross-lane exchange needed.
// ---------------------------------------------------------------------------
__global__ __launch_bounds__(256) void lstm_step_k(
    const u16* __restrict__ hpA, const u16* __restrict__ xgA, const u16* __restrict__ whA,
    float* __restrict__ cA, u16* __restrict__ hoA,
    const u16* __restrict__ hpB, const u16* __restrict__ xgB, const u16* __restrict__ whB,
    float* __restrict__ cB, u16* __restrict__ hoB,
    long hp_stride, long ho_stride, int first) {
  const u16* hp; const u16* xg; const u16* wh; float* c; u16* ho;
  if (blockIdx.z == 0) { hp = hpA; xg = xgA; wh = whA; c = cA; ho = hoA; }
  else                 { hp = hpB; xg = xgB; wh = whB; c = cB; ho = hoB; }
  const int lane = threadIdx.x & 63;
  const int wv = threadIdx.x >> 6;
  const int lr = lane & 15, lg = lane >> 4;
  const long rbase = (long)blockIdx.y * 64 + wv * 16;
  const long hbase = (long)blockIdx.x * 16;
  f32x4 acc[4] = {};
  if (!first) {
    for (int kk = 0; kk < 512; kk += 32) {
      const int k0 = kk + lg * 8;
      bf16x8 a = *reinterpret_cast<const bf16x8*>(hp + (rbase + lr) * hp_stride + k0);
#pragma unroll
      for (int g = 0; g < 4; g++) {
        bf16x8 b = *reinterpret_cast<const bf16x8*>(wh + ((long)g * 512 + hbase + lr) * 512 + k0);
        acc[g] = __builtin_amdgcn_mfma_f32_16x16x32_bf16(a, b, acc[g], 0, 0, 0);
      }
    }
  }
#pragma unroll
  for (int r = 0; r < 4; r++) {
    const long row = rbase + lg * 4 + r;  // batch index
    const long col = hbase + lr;
    const long xrow = row * 2048;
    float gi = acc[0][r] + bf2f(xg[xrow + col]);
    float gf = acc[1][r] + bf2f(xg[xrow + 512 + col]);
    float gg = acc[2][r] + bf2f(xg[xrow + 1024 + col]);
    float go = acc[3][r] + bf2f(xg[xrow + 1536 + col]);
    float cold = first ? 0.f : c[row * 512 + col];
    float cn = sigm(gf) * cold + sigm(gi) * tnh(gg);
    float hn = sigm(go) * tnh(cn);
    c[row * 512 + col] = cn;
    ho[row * ho_stride + col] = f2bf(hn);
  }
}

// ---------------------------------------------------------------------------
// Embedding gathers -> bf16, TIME-MAJOR output (row = t*256 + b).
// ---------------------------------------------------------------------------
__global__ __launch_bounds__(256) void embed_enc_k(
    const int* __restrict__ q, const int* __restrict__ a, const int* __restrict__ pos,
    const int* __restrict__ fmt, const float* __restrict__ tw, const float* __restrict__ aw,
    const float* __restrict__ pw, const float* __restrict__ fw, u16* __restrict__ out) {
  const long blk = blockIdx.x;             // t*256 + b
  const int t = (int)(blk >> 8), b = (int)(blk & 255);
  const long src = (long)b * 256 + t;      // inputs are [B][T]
  const int iq = q[src], ia = a[src], ip = pos[src], ifm = fmt[src];
  for (int col = threadIdx.x; col < 288; col += 256) {
    float v;
    if (col < 128)      v = tw[(long)iq * 128 + col];
    else if (col < 256) v = aw[(long)ia * 128 + (col - 128)];
    else if (col < 272) v = pw[(long)ip * 16 + (col - 256)];
    else                v = fw[(long)ifm * 16 + (col - 272)];
    out[blk * 288 + col] = f2bf(v);
  }
}

__global__ __launch_bounds__(256) void embed_dec_k(
    const int* __restrict__ q, const int* __restrict__ a, const int* __restrict__ pos,
    const int* __restrict__ fmt, const int* __restrict__ last_a,
    const float* __restrict__ tw, const float* __restrict__ aw,
    const float* __restrict__ pw, const float* __restrict__ fw, u16* __restrict__ out) {
  const long blk = blockIdx.x;             // t*256 + b
  const int t = (int)(blk >> 8), b = (int)(blk & 255);
  const long src = (long)b * 256 + t;
  const int iq = q[src], ip = pos[src], ifm = fmt[src];
  const int pa = (t == 0) ? last_a[b] : a[src - 1];  // teacher forcing shift
  for (int col = threadIdx.x; col < 288; col += 256) {
    float v;
    if (col < 128)      v = tw[(long)iq * 128 + col];
    else if (col < 144) v = pw[(long)ip * 16 + (col - 128)];
    else if (col < 160) v = fw[(long)ifm * 16 + (col - 144)];
    else                v = aw[(long)pa * 128 + (col - 160)];
    out[blk * 288 + col] = f2bf(v);
  }
}

// out[b*256 + t0 + tl] = sigmoid(hidden[row] . w2 + b2); row = tl*256 + b.
__global__ __launch_bounds__(256) void pred_out_k(
    const u16* __restrict__ hidden, const float* __restrict__ w2,
    const float* __restrict__ b2, float* __restrict__ out, int t0) {
  const long r = (long)blockIdx.x * 4 + (threadIdx.x >> 6);
  const int lane = threadIdx.x & 63;
  const u16* hp = hidden + r * 512 + lane * 8;
  const float* wp = w2 + lane * 8;
  float s = 0.f;
#pragma unroll
  for (int j = 0; j < 8; j++) s += bf2f(hp[j]) * wp[j];
  for (int off = 32; off > 0; off >>= 1) s += __shfl_down(s, off);
  if (lane == 0) out[(r & 255) * 256 + t0 + (r >> 8)] = sigm(s + b2[0]);
}

__global__ __launch_bounds__(256) void conv_bf16_k(const float* __restrict__ s,
                                                   u16* __restrict__ d, long n) {
  long i = (long)blockIdx.x * 256 + threadIdx.x;
  if (i < n) d[i] = f2bf(s[i]);
}
__global__ __launch_bounds__(256) void bias_sum_k(const float* __restrict__ a,
                                                  const float* __restrict__ b,
                                                  float* __restrict__ d, int n) {
  int i = blockIdx.x * 256 + threadIdx.x;
  if (i < n) d[i] = a[i] + b[i];
}

// ---------------------------------------------------------------------------
extern "C" void kernel_launch(void* const* d_in, const int* in_sizes, int n_in,
                              void* d_out, int out_size, void* d_ws, size_t ws_size,
                              hipStream_t stream) {
  const int* enc_q     = (const int*)d_in[0];
  const int* enc_a     = (const int*)d_in[1];
  const int* enc_pos   = (const int*)d_in[2];
  const int* enc_fmt   = (const int*)d_in[3];
  const int* dec_q     = (const int*)d_in[4];
  const int* dec_a     = (const int*)d_in[5];
  const int* dec_pos   = (const int*)d_in[6];
  const int* dec_fmt   = (const int*)d_in[7];
  const int* enc_last  = (const int*)d_in[8];
  const float* t_emb   = (const float*)d_in[9];
  const float* a_emb   = (const float*)d_in[10];
  const float* pos_emb = (const float*)d_in[11];
  const float* fmt_emb = (const float*)d_in[12];
  const float* bif_w_ih = (const float*)d_in[13];
  const float* bif_w_hh = (const float*)d_in[14];
  const float* bif_b_ih = (const float*)d_in[15];
  const float* bif_b_hh = (const float*)d_in[16];
  const float* bib_w_ih = (const float*)d_in[17];
  const float* bib_w_hh = (const float*)d_in[18];
  const float* bib_b_ih = (const float*)d_in[19];
  const float* bib_b_hh = (const float*)d_in[20];
  const float* enc_w_ih = (const float*)d_in[21];
  const float* enc_w_hh = (const float*)d_in[22];
  const float* enc_b_ih = (const float*)d_in[23];
  const float* enc_b_hh = (const float*)d_in[24];
  const float* dec_w_ih = (const float*)d_in[25];
  const float* dec_w_hh = (const float*)d_in[26];
  const float* dec_b_ih = (const float*)d_in[27];
  const float* dec_b_hh = (const float*)d_in[28];
  const float* pred_w1 = (const float*)d_in[29];
  const float* pred_b1 = (const float*)d_in[30];
  const float* pred_w2 = (const float*)d_in[31];
  const float* pred_b2 = (const float*)d_in[32];
  (void)in_sizes; (void)n_in; (void)out_size;

  char* base = (char*)d_ws;
  size_t off = 0;
  auto alloc = [&](size_t bytes) -> char* {
    char* p = base + off;
    off = (off + bytes + 255) & ~(size_t)255;
    return p;
  };

  // --- fixed region: bf16 weights, biases, states (~19 MB) ---
  u16* wb_bif_ih = (u16*)alloc(2048L * 288 * 2);
  u16* wb_bib_ih = (u16*)alloc(2048L * 288 * 2);
  u16* wb_enc_ih = (u16*)alloc(2048L * 1024 * 2);
  u16* wb_dec_ih = (u16*)alloc(2048L * 288 * 2);
  u16* wb_bif_hh = (u16*)alloc(2048L * 512 * 2);
  u16* wb_bib_hh = (u16*)alloc(2048L * 512 * 2);
  u16* wb_enc_hh = (u16*)alloc(2048L * 512 * 2);
  u16* wb_dec_hh = (u16*)alloc(2048L * 512 * 2);
  u16* wb_pred1  = (u16*)alloc(512L * 672 * 2);
  float* bias_bif = (float*)alloc(2048 * 4);
  float* bias_bib = (float*)alloc(2048 * 4);
  float* bias_enc = (float*)alloc(2048 * 4);
  float* bias_dec = (float*)alloc(2048 * 4);
  float* c_bif = (float*)alloc(256L * 512 * 4);
  float* c_bib = (float*)alloc(256L * 512 * 4);
  float* c_enc = (float*)alloc(256L * 512 * 4);  // enc, then dec continues in it
  u16* h_enc0 = (u16*)alloc(256L * 512 * 2);
  u16* h_enc1 = (u16*)alloc(256L * 512 * 2);

  // --- big activations (time-major) ---
  u16* bi    = (u16*)alloc(65536L * 1024 * 2);  // [T][B][fwd 512 | bwd 512]  134 MB
  u16* dec_x = (u16*)alloc(65536L * 288 * 2);   // 37.7 MB, live until head
  u16* enc_x = (u16*)alloc(65536L * 288 * 2);   // 37.7 MB, dead after phase 1
                                                // -> overlaid by decout+hidden

  // --- chunk size chosen from remaining workspace (deterministic) ---
  int CH = 32;
  while (CH > 4 && off + 2ull * CH * 256 * 2048 * 2 > ws_size) CH >>= 1;
  u16* X1 = (u16*)alloc((size_t)CH * 256 * 2048 * 2);  // xg chunk A
  u16* X2 = (u16*)alloc((size_t)CH * 256 * 2048 * 2);  // xg chunk B
  u16* decout = enc_x;                                  // CH-slot ring [CH][B][512]
  u16* hidden = enc_x + (long)CH * 256 * 512;           // [CH*B][512]
  const int NCH = 256 / CH;
  const long SLOT_XG = 256L * 2048;   // one timestep of xg
  const long SLOT_BI = 256L * 1024;   // one timestep of bi
  const long SLOT_DO = 256L * 512;    // one timestep of decout

  auto CV = [&](const float* s, u16* d, long n) {
    conv_bf16_k<<<dim3((unsigned)((n + 255) / 256)), dim3(256), 0, stream>>>(s, d, n);
  };
  CV(bif_w_ih, wb_bif_ih, 2048L * 288);
  CV(bib_w_ih, wb_bib_ih, 2048L * 288);
  CV(enc_w_ih, wb_enc_ih, 2048L * 1024);
  CV(dec_w_ih, wb_dec_ih, 2048L * 288);
  CV(bif_w_hh, wb_bif_hh, 2048L * 512);
  CV(bib_w_hh, wb_bib_hh, 2048L * 512);
  CV(enc_w_hh, wb_enc_hh, 2048L * 512);
  CV(dec_w_hh, wb_dec_hh, 2048L * 512);
  CV(pred_w1, wb_pred1, 512L * 672);
  bias_sum_k<<<8, 256, 0, stream>>>(bif_b_ih, bif_b_hh, bias_bif, 2048);
  bias_sum_k<<<8, 256, 0, stream>>>(bib_b_ih, bib_b_hh, bias_bib, 2048);
  bias_sum_k<<<8, 256, 0, stream>>>(enc_b_ih, enc_b_hh, bias_enc, 2048);
  bias_sum_k<<<8, 256, 0, stream>>>(dec_b_ih, dec_b_hh, bias_dec, 2048);

  embed_enc_k<<<65536, 256, 0, stream>>>(enc_q, enc_a, enc_pos, enc_fmt,
                                         t_emb, a_emb, pos_emb, fmt_emb, enc_x);
  embed_dec_k<<<65536, 256, 0, stream>>>(dec_q, dec_a, dec_pos, dec_fmt, enc_last,
                                         t_emb, a_emb, pos_emb, fmt_emb, dec_x);

  // ---- phase 1: bif (fwd, t ascending) + bib (bwd, t2 descending) into `bi`
  for (int k = 0; k < NCH; k++) {
    const int t0f = k * CH;
    const int t0b = 256 - (k + 1) * CH;
    gemm_k<0><<<dim3(32, CH * 4), 256, 0, stream>>>(
        enc_x + (long)t0f * 256 * 288, 288, enc_x, 288, 288,
        wb_bif_ih, 288, bias_bif, X1, 2048, 288);
    gemm_k<0><<<dim3(32, CH * 4), 256, 0, stream>>>(
        enc_x + (long)t0b * 256 * 288, 288, enc_x, 288, 288,
        wb_bib_ih, 288, bias_bib, X2, 2048, 288);
    for (int s = k * CH; s < (k + 1) * CH; s++) {
      const int t = s, t2 = 255 - s;
      lstm_step_k<<<dim3(32, 4, 2), 256, 0, stream>>>(
          bi + (long)(t - 1) * SLOT_BI, X1 + (long)(t & (CH - 1)) * SLOT_XG, wb_bif_hh,
          c_bif, bi + (long)t * SLOT_BI,
          bi + (long)(t2 + 1) * SLOT_BI + 512, X2 + (long)(t2 & (CH - 1)) * SLOT_XG, wb_bib_hh,
          c_bib, bi + (long)t2 * SLOT_BI + 512,
          1024L, 1024L, s == 0 ? 1 : 0);
    }
  }

  // ---- phase 2: enc LSTM over bi (only final state kept)
  for (int k = 0; k < NCH; k++) {
    const int t0 = k * CH;
    gemm_k<0><<<dim3(32, CH * 4), 256, 0, stream>>>(
        bi + (long)t0 * SLOT_BI, 1024, bi, 1024, 1024,
        wb_enc_ih, 1024, bias_enc, X1, 2048, 1024);
    for (int s = t0; s < t0 + CH; s++) {
      const u16* hp = (s & 1) ? h_enc1 : h_enc0;
      u16* ho = (s & 1) ? h_enc0 : h_enc1;
      lstm_step_k<<<dim3(32, 4, 1), 256, 0, stream>>>(
          hp, X1 + (long)(s & (CH - 1)) * SLOT_XG, wb_enc_hh, c_enc, ho,
          nullptr, nullptr, nullptr, nullptr, nullptr,
          512L, 512L, s == 0 ? 1 : 0);
    }
  }
  // final h in h_enc0 (256 even), final c in c_enc

  // ---- phase 3: dec LSTM + per-chunk prediction head
  for (int k = 0; k < NCH; k++) {
    const int t0 = k * CH;
    gemm_k<0><<<dim3(32, CH * 4), 256, 0, stream>>>(
        dec_x + (long)t0 * 256 * 288, 288, dec_x, 288, 288,
        wb_dec_ih, 288, bias_dec, X1, 2048, 288);
    for (int t = t0; t < t0 + CH; t++) {
      const u16* hp = (t == 0) ? h_enc0 : (decout + (long)((t - 1) & (CH - 1)) * SLOT_DO);
      lstm_step_k<<<dim3(32, 4, 1), 256, 0, stream>>>(
          hp, X1 + (long)(t & (CH - 1)) * SLOT_XG, wb_dec_hh, c_enc,
          decout + (long)(t & (CH - 1)) * SLOT_DO,
          nullptr, nullptr, nullptr, nullptr, nullptr,
          512L, 512L, 0);
    }
    // head for this chunk: hidden = tanh([dec_x[:, :160] | decout] @ w1^T + b1)
    gemm_k<1><<<dim3(8, CH * 4), 256, 0, stream>>>(
        dec_x + (long)t0 * 256 * 288, 288, decout, 512, 160,
        wb_pred1, 672, pred_b1, hidden, 512, 672);
    pred_out_k<<<CH * 64, 256, 0, stream>>>(hidden, pred_w2, pred_b2, (float*)d_out, t0);
  }
}